// Round 6
// baseline (508.648 us; speedup 1.0000x reference)
//
#include <hip/hip_runtime.h>
#include <hip/hip_bf16.h>
#include <math.h>

typedef short s16x4 __attribute__((ext_vector_type(4)));
typedef short bf16x8 __attribute__((ext_vector_type(8)));
typedef float f32x16 __attribute__((ext_vector_type(16)));

#define C_IN 273
#define C_OUT 270
#define T_DIM 2048
#define KP 288            // padded C_in
#define APR_STRIDE 288    // elements per aperm row (576 B)
#define APR_ROWS 320

// ---------- workspace offsets (Xt path) ----------
#define XT_ROW 576u                     // bytes per Xt row (288 bf16)
#define XT_PER_B 1179648u               // 2048 * 576
#define WS2_COS   150994944u
#define WS2_SIN   152113152u
#define WS2_PART  153231360u
#define WS2_APERM 155738112u
#define WS2_END   155922432u

// ---------- old-path (fallback) offsets ----------
#define WS_COS 0u
#define WS_SIN 1118208u
#define WS_PART 2236416u
#define WS_APERM 4743168u
#define ALD_STRIDE 592
#define A_LDS_BYTES (64 * ALD_STRIDE)
#define XBUF_BYTES 8192

__device__ __forceinline__ short f2bf(float f) {
  __hip_bfloat16 h = __float2bfloat16(f);
  short r; __builtin_memcpy(&r, &h, 2); return r;
}

// ---------------- kernel 1a: Fourier basis ----------------
__global__ void k_basis(const float* __restrict__ x, const float* __restrict__ y,
                        float* __restrict__ cosb, float* __restrict__ sinb) {
  const int i = blockIdx.x;
  const float xi = x[i], yi = y[i];
  const int base = threadIdx.x * 4;
  #pragma unroll
  for (int j = 0; j < 4; ++j) {
    const int kl = base + j;
    const float kf = (float)((kl & 31) + 1);
    const float lf = (float)((kl >> 5) + 1);
    const float ph = 6.28318530717958647692f * (kf * xi + lf * yi);
    float sn, cs;
    sincosf(ph, &sn, &cs);
    cosb[(size_t)i * 1024 + kl] = cs;
    sinb[(size_t)i * 1024 + kl] = sn;
  }
}

// ---------------- kernel 1b: logits partials ----------------
__global__ __launch_bounds__(256) void k_logits(const float* __restrict__ zr,
    const float* __restrict__ zi, const float* __restrict__ cosb,
    const float* __restrict__ sinb, float* __restrict__ part) {
  const int tx = threadIdx.x & 15, ty = threadIdx.x >> 4;
  const int ibase = blockIdx.x * 64 + tx * 4;
  const int obase = blockIdx.y * 64 + ty * 4;
  const int kl0 = (int)blockIdx.z * 128;
  int oc[4], ic[4];
  #pragma unroll
  for (int a = 0; a < 4; ++a) {
    oc[a] = min(obase + a, C_OUT - 1);
    ic[a] = min(ibase + a, C_IN - 1);
  }
  float acc[4][4] = {};
  for (int kl = kl0; kl < kl0 + 128; kl += 4) {
    float4 zr4[4], zi4[4], cb4[4], sb4[4];
    #pragma unroll
    for (int a = 0; a < 4; ++a) {
      zr4[a] = *(const float4*)(zr + (size_t)oc[a] * 1024 + kl);
      zi4[a] = *(const float4*)(zi + (size_t)oc[a] * 1024 + kl);
    }
    #pragma unroll
    for (int b = 0; b < 4; ++b) {
      cb4[b] = *(const float4*)(cosb + (size_t)ic[b] * 1024 + kl);
      sb4[b] = *(const float4*)(sinb + (size_t)ic[b] * 1024 + kl);
    }
    #pragma unroll
    for (int a = 0; a < 4; ++a)
      #pragma unroll
      for (int b = 0; b < 4; ++b)
        acc[a][b] += zr4[a].x * cb4[b].x + zr4[a].y * cb4[b].y
                   + zr4[a].z * cb4[b].z + zr4[a].w * cb4[b].w
                   + zi4[a].x * sb4[b].x + zi4[a].y * sb4[b].y
                   + zi4[a].z * sb4[b].z + zi4[a].w * sb4[b].w;
  }
  #pragma unroll
  for (int a = 0; a < 4; ++a)
    #pragma unroll
    for (int b = 0; b < 4; ++b) {
      const int o = obase + a, i = ibase + b;
      if (o < C_OUT && i < C_IN)
        part[((size_t)blockIdx.z * 272 + o) * 288 + i] = acc[a][b];
    }
}

// ---------------- kernel 1c: mask + softmax + bf16 store ----------------
__global__ __launch_bounds__(256) void k_softmax(const float* __restrict__ part,
    const float* __restrict__ x, const float* __restrict__ y,
    const float* __restrict__ xdp, const float* __restrict__ ydp,
    __hip_bfloat16* __restrict__ aperm, int perm) {
  const int o = blockIdx.x;
  const int tid = threadIdx.x;
  if (o >= C_OUT) {
    for (int s = tid; s < KP; s += 256)
      aperm[(size_t)o * APR_STRIDE + s] = __float2bfloat16(0.f);
    return;
  }
  __shared__ float red[8];
  const float xd = xdp[0], yd = ydp[0];
  const int i0 = tid, i1 = tid + 256;
  float v0, v1 = 0.f;
  {
    float s = 0.f;
    #pragma unroll
    for (int c = 0; c < 8; ++c) s += part[((size_t)c * 272 + o) * 288 + i0];
    const float dx = xd - x[i0], dy = yd - y[i0];
    v0 = (dx * dx + dy * dy < 0.1f) ? 0.f : s;
  }
  const bool has1 = (i1 < C_IN);
  if (has1) {
    float s = 0.f;
    #pragma unroll
    for (int c = 0; c < 8; ++c) s += part[((size_t)c * 272 + o) * 288 + i1];
    const float dx = xd - x[i1], dy = yd - y[i1];
    v1 = (dx * dx + dy * dy < 0.1f) ? 0.f : s;
  }
  float mv = has1 ? fmaxf(v0, v1) : v0;
  #pragma unroll
  for (int off = 32; off >= 1; off >>= 1) mv = fmaxf(mv, __shfl_down(mv, off));
  if ((tid & 63) == 0) red[tid >> 6] = mv;
  __syncthreads();
  const float M = fmaxf(fmaxf(red[0], red[1]), fmaxf(red[2], red[3]));
  const float e0 = expf(v0 - M);
  const float e1 = has1 ? expf(v1 - M) : 0.f;
  float sv = e0 + e1;
  #pragma unroll
  for (int off = 32; off >= 1; off >>= 1) sv += __shfl_down(sv, off);
  __syncthreads();
  if ((tid & 63) == 0) red[4 + (tid >> 6)] = sv;
  __syncthreads();
  const float S = red[4] + red[5] + red[6] + red[7];
  const float inv = 1.0f / S;
  {
    const int s = perm ? ((i0 & ~3) | ((i0 & 3) ^ ((i0 >> 2) & 3))) : i0;
    aperm[(size_t)o * APR_STRIDE + s] = __float2bfloat16(e0 * inv);
  }
  if (i1 < KP) {
    const int s = perm ? ((i1 & ~3) | ((i1 & 3) ^ ((i1 >> 2) & 3))) : i1;
    aperm[(size_t)o * APR_STRIDE + s] = __float2bfloat16(has1 ? e1 * inv : 0.f);
  }
}

// ---------------- kernel T: transpose+cast X -> Xt[b][t][i] via LDS tile ----------------
// Block: 64 t x 288 i. Reads coalesced (wave = 64 consecutive t), writes
// contiguous 36 KB per block. LDS row stride 596 B (149 words, gcd(21,32)=1).
__global__ __launch_bounds__(256) void k_trans(const float* __restrict__ X,
                                               char* __restrict__ Xt) {
  __shared__ __align__(16) char lds[64 * 596];
  const int tid = threadIdx.x;
  const int t0 = blockIdx.x * 64;
  const int b = blockIdx.y;
  const float* Xb = X + (size_t)b * C_IN * T_DIM;
  const int tt = tid & 63, ig = tid >> 6;        // wave = fixed ig, t consecutive
  #pragma unroll 4
  for (int p = 0; p < 36; ++p) {
    const int i = p * 8 + ig * 2;
    const float v0 = (i < C_IN) ? Xb[(size_t)i * T_DIM + t0 + tt] : 0.f;
    const float v1 = (i + 1 < C_IN) ? Xb[(size_t)(i + 1) * T_DIM + t0 + tt] : 0.f;
    const unsigned pk = (unsigned)(unsigned short)f2bf(v0)
                      | ((unsigned)(unsigned short)f2bf(v1) << 16);
    *(unsigned*)(lds + tt * 596 + i * 2) = pk;
  }
  __syncthreads();
  const int r = tid >> 2, c = tid & 3;
  char* dst = Xt + (size_t)b * XT_PER_B + (size_t)(t0 + r) * XT_ROW + c * 144;
  const char* src = lds + r * 596 + c * 144;
  #pragma unroll
  for (int j = 0; j < 9; ++j)
    *(float4*)(dst + j * 16) = *(const float4*)(src + j * 16);
}

// ---------------- kernel 2: out[b] = a @ X[b], LDS-free streaming MFMA ----------------
// Depth-3 register pipeline, PINNED with sched_barrier(0) so the scheduler
// cannot sink loads to their uses (round-5 failure: VGPR=44 proved depth-0).
__global__ __launch_bounds__(256) void k_gemm2(const __hip_bfloat16* __restrict__ aperm,
    const char* __restrict__ Xt, float* __restrict__ out) {
  const int tid = threadIdx.x;
  const int lane = tid & 63, w = tid >> 6;
  const int l32 = lane & 31, lh = lane >> 5;
  const int ob = blockIdx.x;   // 0..2  (fastest: ob-sharers adjacent for L2)
  const int tb = blockIdx.y;   // 0..15
  const int b  = blockIdx.z;   // 0..127

  const int t = tb * 128 + w * 32 + l32;
  const char* Brow  = Xt + (size_t)b * XT_PER_B + (size_t)t * XT_ROW + lh * 16;
  const char* Arow0 = (const char*)aperm + (size_t)(ob * 96 + l32) * 576 + lh * 16;
  const char* Arow1 = Arow0 + 32 * 576;
  const char* Arow2 = Arow0 + 64 * 576;

  f32x16 acc[3] = {};
  bf16x8 Bf[3], Af[3][3];

  // prologue: issue kk = 0, 1
  Bf[0] = *(const bf16x8*)(Brow);
  Af[0][0] = *(const bf16x8*)(Arow0);
  Af[0][1] = *(const bf16x8*)(Arow1);
  Af[0][2] = *(const bf16x8*)(Arow2);
  Bf[1] = *(const bf16x8*)(Brow + 32);
  Af[1][0] = *(const bf16x8*)(Arow0 + 32);
  Af[1][1] = *(const bf16x8*)(Arow1 + 32);
  Af[1][2] = *(const bf16x8*)(Arow2 + 32);
  __builtin_amdgcn_sched_barrier(0);

  #pragma unroll
  for (int kk = 0; kk < 18; ++kk) {
    const int cur = kk % 3;
    if (kk + 2 < 18) {
      const int nxt = (kk + 2) % 3;
      const int off = (kk + 2) * 32;
      Bf[nxt]    = *(const bf16x8*)(Brow  + off);
      Af[nxt][0] = *(const bf16x8*)(Arow0 + off);
      Af[nxt][1] = *(const bf16x8*)(Arow1 + off);
      Af[nxt][2] = *(const bf16x8*)(Arow2 + off);
    }
    __builtin_amdgcn_sched_barrier(0);    // loads for kk+2 stay >=2 regions early
    acc[0] = __builtin_amdgcn_mfma_f32_32x32x16_bf16(Af[cur][0], Bf[cur], acc[0], 0, 0, 0);
    acc[1] = __builtin_amdgcn_mfma_f32_32x32x16_bf16(Af[cur][1], Bf[cur], acc[1], 0, 0, 0);
    acc[2] = __builtin_amdgcn_mfma_f32_32x32x16_bf16(Af[cur][2], Bf[cur], acc[2], 0, 0, 0);
    __builtin_amdgcn_sched_barrier(0);
  }

  // epilogue: C/D layout (32x32): col = l&31 -> t, row = (r&3) + 8*(r>>2) + 4*lh
  float* outb = out + (size_t)b * C_OUT * T_DIM;
  #pragma unroll
  for (int mi = 0; mi < 3; ++mi)
    #pragma unroll
    for (int r = 0; r < 16; ++r) {
      const int o = ob * 96 + mi * 32 + (r & 3) + 8 * (r >> 2) + 4 * lh;
      if (o < C_OUT)
        outb[(size_t)o * T_DIM + t] = acc[mi][r];
    }
}

// ---------------- OLD kernel 2 (fallback if ws too small) ----------------
__device__ __forceinline__ void load_chunk(const float* __restrict__ Xb, int ch,
                                           int t_base, int tid, float4 (&r)[4]) {
  const int k4 = tid & 7, t4 = tid >> 3;
  const int t = t_base + t4 * 4;
  #pragma unroll
  for (int rr = 0; rr < 4; ++rr) {
    const int i = ch * 32 + k4 * 4 + rr;
    float4 v = make_float4(0.f, 0.f, 0.f, 0.f);
    if (i < C_IN) v = *(const float4*)(Xb + (size_t)i * T_DIM + t);
    r[rr] = v;
  }
}

__device__ __forceinline__ void write_chunk(char* __restrict__ xb, int tid,
                                            const float4 (&r)[4]) {
  const int k4 = tid & 7, t4 = tid >> 3;
  const int tb = t4 >> 2, c4 = t4 & 3;
  #pragma unroll
  for (int rr = 0; rr < 4; ++rr) {
    const int j = rr ^ (k4 & 3);
    s16x4 p;
    p[0] = f2bf(r[rr].x); p[1] = f2bf(r[rr].y);
    p[2] = f2bf(r[rr].z); p[3] = f2bf(r[rr].w);
    *(s16x4*)(xb + (k4 * 8 + tb) * 128 + j * 32 + c4 * 8) = p;
  }
}

__global__ __launch_bounds__(256) void k_gemm_old(const float* __restrict__ X,
    const __hip_bfloat16* __restrict__ aperm, float* __restrict__ out) {
  __shared__ __align__(16) char smem[A_LDS_BYTES + 2 * XBUF_BYTES];
  const int tid = threadIdx.x;
  const int lane = tid & 63, w = tid >> 6;
  const int bid = blockIdx.x;
  const int xcd = bid & 7, slot = bid >> 3;
  const int bat = slot / 80;
  const int idx = slot - bat * 80;
  const int b   = bat * 8 + xcd;
  const int oy  = idx % 5;
  const int tx  = idx / 5;
  const int o_base = oy * 64;
  const int t_base = tx * 128;
  const float* Xb = X + (size_t)b * C_IN * T_DIM;

  {
    const int row = tid >> 2, q = tid & 3;
    const float4* src = (const float4*)((const char*)(aperm + (size_t)(o_base + row) * APR_STRIDE) + q * 144);
    float4* dst = (float4*)(smem + row * ALD_STRIDE + q * 144);
    #pragma unroll
    for (int v = 0; v < 9; ++v) dst[v] = src[v];
  }

  f32x16 acc[2] = {};
  const unsigned smem_u = (unsigned)(unsigned long long)(uintptr_t)smem;
  const unsigned xlds0 = smem_u + A_LDS_BYTES;
  const int lg = lane >> 4, l16 = lane & 15, l32 = lane & 31, lh = lane >> 5;
  const unsigned bconst = (unsigned)((lg >> 1) * 2048 + (lg & 1) * 128 + w * 256 + l16 * 8);

  char* xb0 = smem + A_LDS_BYTES;
  char* xb1 = smem + A_LDS_BYTES + XBUF_BYTES;

  float4 rA[4], rB[4];
  load_chunk(Xb, 0, t_base, tid, rA);
  load_chunk(Xb, 1, t_base, tid, rB);
  write_chunk(xb0, tid, rA);
  __syncthreads();

  #define COMPUTE(CH, BUFSEL)                                                      \
    {                                                                              \
      const unsigned xb = xlds0 + (BUFSEL) * XBUF_BYTES + bconst;                  \
      const char* arow0 = smem + l32 * ALD_STRIDE + ((CH) * 32) * 2 + lh * 16;     \
      _Pragma("unroll")                                                            \
      for (int kk = 0; kk < 32; kk += 16) {                                        \
        bf16x8 A0 = *(const bf16x8*)(arow0 + kk * 2);                              \
        bf16x8 A1 = *(const bf16x8*)(arow0 + 32 * ALD_STRIDE + kk * 2);            \
        s16x4 t0, t1;                                                              \
        const unsigned a0 = xb + kk * 256;                                         \
        asm volatile("ds_read_b64_tr_b16 %0, %1" : "=v"(t0) : "v"(a0));            \
        asm volatile("ds_read_b64_tr_b16 %0, %1 offset:1024" : "=v"(t1) : "v"(a0));\
        asm volatile("s_waitcnt lgkmcnt(0)" ::: "memory");                         \
        __builtin_amdgcn_sched_barrier(0);                                         \
        bf16x8 B0;                                                                 \
        B0[0] = t0[0]; B0[1] = t0[1]; B0[2] = t0[2]; B0[3] = t0[3];                \
        B0[4] = t1[0]; B0[5] = t1[1]; B0[6] = t1[2]; B0[7] = t1[3];                \
        acc[0] = __builtin_amdgcn_mfma_f32_32x32x16_bf16(A0, B0, acc[0], 0, 0, 0); \
        acc[1] = __builtin_amdgcn_mfma_f32_32x32x16_bf16(A1, B0, acc[1], 0, 0, 0); \
      }                                                                            \
    }

  for (int ch = 0; ch < 9; ch += 2) {
    if (ch + 2 < 9) load_chunk(Xb, ch + 2, t_base, tid, rA);
    COMPUTE(ch, 0)
    if (ch + 1 < 9) write_chunk(xb1, tid, rB);
    __syncthreads();
    if (ch + 1 < 9) {
      if (ch + 3 < 9) load_chunk(Xb, ch + 3, t_base, tid, rB);
      COMPUTE(ch + 1, 1)
      if (ch + 2 < 9) write_chunk(xb0, tid, rA);
      __syncthreads();
    }
  }
  #undef COMPUTE

  float* outb = out + (size_t)b * C_OUT * T_DIM;
  #pragma unroll
  for (int m = 0; m < 2; ++m)
    #pragma unroll
    for (int r = 0; r < 16; ++r) {
      const int o = o_base + m * 32 + (r & 3) + 8 * (r >> 2) + 4 * lh;
      if (o < C_OUT) {
        const int t = t_base + w * 32 + l32;
        outb[(size_t)o * T_DIM + t] = acc[m][r];
      }
    }
}

extern "C" void kernel_launch(void* const* d_in, const int* in_sizes, int n_in,
                              void* d_out, int out_size, void* d_ws, size_t ws_size,
                              hipStream_t stream) {
  const float* X  = (const float*)d_in[0];
  const float* zr = (const float*)d_in[1];
  const float* zi = (const float*)d_in[2];
  const float* x  = (const float*)d_in[3];
  const float* y  = (const float*)d_in[4];
  const float* xd = (const float*)d_in[5];
  const float* yd = (const float*)d_in[6];
  float* out = (float*)d_out;
  char* ws = (char*)d_ws;

  const bool big = ws_size >= (size_t)WS2_END;
  if (big) {
    float* cosb = (float*)(ws + WS2_COS);
    float* sinb = (float*)(ws + WS2_SIN);
    float* part = (float*)(ws + WS2_PART);
    __hip_bfloat16* aperm = (__hip_bfloat16*)(ws + WS2_APERM);
    char* Xt = ws;  // offset 0, 151 MB

    k_basis<<<dim3(273), dim3(256), 0, stream>>>(x, y, cosb, sinb);
    k_logits<<<dim3(5, 5, 8), dim3(256), 0, stream>>>(zr, zi, cosb, sinb, part);
    k_softmax<<<dim3(APR_ROWS), dim3(256), 0, stream>>>(part, x, y, xd, yd, aperm, 0);
    k_trans<<<dim3(32, 128), dim3(256), 0, stream>>>(X, Xt);
    k_gemm2<<<dim3(3, 16, 128), dim3(256), 0, stream>>>(aperm, Xt, out);
  } else {
    float* cosb = (float*)(ws + WS_COS);
    float* sinb = (float*)(ws + WS_SIN);
    float* part = (float*)(ws + WS_PART);
    __hip_bfloat16* aperm = (__hip_bfloat16*)(ws + WS_APERM);

    k_basis<<<dim3(273), dim3(256), 0, stream>>>(x, y, cosb, sinb);
    k_logits<<<dim3(5, 5, 8), dim3(256), 0, stream>>>(zr, zi, cosb, sinb, part);
    k_softmax<<<dim3(APR_ROWS), dim3(256), 0, stream>>>(part, x, y, xd, yd, aperm, 1);
    k_gemm_old<<<dim3(10240), dim3(256), 0, stream>>>(X, aperm, out);
  }
}

// Round 7
// 395.142 us; speedup vs baseline: 1.2873x; 1.2873x over previous
//
#include <hip/hip_runtime.h>
#include <hip/hip_bf16.h>
#include <math.h>

typedef short s16x4 __attribute__((ext_vector_type(4)));
typedef short bf16x8 __attribute__((ext_vector_type(8)));
typedef float f32x16 __attribute__((ext_vector_type(16)));

#define C_IN 273
#define C_OUT 270
#define T_DIM 2048
#define KP 288            // padded C_in (18 k-slices of 16)
#define NKS 18

// ---------- workspace layout ----------
// Xt: bf16 [b][ks:18][t:2048][k:16]  (coalesced GEMM B-fragments)
#define XT_KS_STRIDE 65536u             // 2048*16*2 bytes
#define XT_PER_B 1179648u               // 18*65536
#define WS2_COS   150994944u
#define WS2_SIN   152113152u
#define WS2_PART  153231360u
#define WS2_APERM 155738112u            // bf16 [ks:18][o:288][k:16] = 165888 B
#define APR2_KS_STRIDE 9216u            // 288*16*2 bytes

__device__ __forceinline__ short f2bf(float f) {
  __hip_bfloat16 h = __float2bfloat16(f);
  short r; __builtin_memcpy(&r, &h, 2); return r;
}

// ---------------- kernel 1a: Fourier basis ----------------
__global__ void k_basis(const float* __restrict__ x, const float* __restrict__ y,
                        float* __restrict__ cosb, float* __restrict__ sinb) {
  const int i = blockIdx.x;
  const float xi = x[i], yi = y[i];
  const int base = threadIdx.x * 4;
  #pragma unroll
  for (int j = 0; j < 4; ++j) {
    const int kl = base + j;
    const float kf = (float)((kl & 31) + 1);
    const float lf = (float)((kl >> 5) + 1);
    const float ph = 6.28318530717958647692f * (kf * xi + lf * yi);
    float sn, cs;
    sincosf(ph, &sn, &cs);
    cosb[(size_t)i * 1024 + kl] = cs;
    sinb[(size_t)i * 1024 + kl] = sn;
  }
}

// ---------------- kernel 1b: logits partials ----------------
__global__ __launch_bounds__(256) void k_logits(const float* __restrict__ zr,
    const float* __restrict__ zi, const float* __restrict__ cosb,
    const float* __restrict__ sinb, float* __restrict__ part) {
  const int tx = threadIdx.x & 15, ty = threadIdx.x >> 4;
  const int ibase = blockIdx.x * 64 + tx * 4;
  const int obase = blockIdx.y * 64 + ty * 4;
  const int kl0 = (int)blockIdx.z * 128;
  int oc[4], ic[4];
  #pragma unroll
  for (int a = 0; a < 4; ++a) {
    oc[a] = min(obase + a, C_OUT - 1);
    ic[a] = min(ibase + a, C_IN - 1);
  }
  float acc[4][4] = {};
  for (int kl = kl0; kl < kl0 + 128; kl += 4) {
    float4 zr4[4], zi4[4], cb4[4], sb4[4];
    #pragma unroll
    for (int a = 0; a < 4; ++a) {
      zr4[a] = *(const float4*)(zr + (size_t)oc[a] * 1024 + kl);
      zi4[a] = *(const float4*)(zi + (size_t)oc[a] * 1024 + kl);
    }
    #pragma unroll
    for (int b = 0; b < 4; ++b) {
      cb4[b] = *(const float4*)(cosb + (size_t)ic[b] * 1024 + kl);
      sb4[b] = *(const float4*)(sinb + (size_t)ic[b] * 1024 + kl);
    }
    #pragma unroll
    for (int a = 0; a < 4; ++a)
      #pragma unroll
      for (int b = 0; b < 4; ++b)
        acc[a][b] += zr4[a].x * cb4[b].x + zr4[a].y * cb4[b].y
                   + zr4[a].z * cb4[b].z + zr4[a].w * cb4[b].w
                   + zi4[a].x * sb4[b].x + zi4[a].y * sb4[b].y
                   + zi4[a].z * sb4[b].z + zi4[a].w * sb4[b].w;
  }
  #pragma unroll
  for (int a = 0; a < 4; ++a)
    #pragma unroll
    for (int b = 0; b < 4; ++b) {
      const int o = obase + a, i = ibase + b;
      if (o < C_OUT && i < C_IN)
        part[((size_t)blockIdx.z * 272 + o) * 288 + i] = acc[a][b];
    }
}

// ---------------- kernel 1c: mask + softmax -> aperm2[ks][o][k] bf16 ----------------
__global__ __launch_bounds__(256) void k_softmax(const float* __restrict__ part,
    const float* __restrict__ x, const float* __restrict__ y,
    const float* __restrict__ xdp, const float* __restrict__ ydp,
    __hip_bfloat16* __restrict__ ap2) {
  const int o = blockIdx.x;            // 0..287
  const int tid = threadIdx.x;
  if (o >= C_OUT) {
    for (int s = tid; s < KP; s += 256)
      ap2[(size_t)((s >> 4) * 288 + o) * 16 + (s & 15)] = __float2bfloat16(0.f);
    return;
  }
  __shared__ float red[8];
  const float xd = xdp[0], yd = ydp[0];
  const int i0 = tid, i1 = tid + 256;
  float v0, v1 = 0.f;
  {
    float s = 0.f;
    #pragma unroll
    for (int c = 0; c < 8; ++c) s += part[((size_t)c * 272 + o) * 288 + i0];
    const float dx = xd - x[i0], dy = yd - y[i0];
    v0 = (dx * dx + dy * dy < 0.1f) ? 0.f : s;
  }
  const bool has1 = (i1 < C_IN);
  if (has1) {
    float s = 0.f;
    #pragma unroll
    for (int c = 0; c < 8; ++c) s += part[((size_t)c * 272 + o) * 288 + i1];
    const float dx = xd - x[i1], dy = yd - y[i1];
    v1 = (dx * dx + dy * dy < 0.1f) ? 0.f : s;
  }
  float mv = has1 ? fmaxf(v0, v1) : v0;
  #pragma unroll
  for (int off = 32; off >= 1; off >>= 1) mv = fmaxf(mv, __shfl_down(mv, off));
  if ((tid & 63) == 0) red[tid >> 6] = mv;
  __syncthreads();
  const float M = fmaxf(fmaxf(red[0], red[1]), fmaxf(red[2], red[3]));
  const float e0 = expf(v0 - M);
  const float e1 = has1 ? expf(v1 - M) : 0.f;
  float sv = e0 + e1;
  #pragma unroll
  for (int off = 32; off >= 1; off >>= 1) sv += __shfl_down(sv, off);
  __syncthreads();
  if ((tid & 63) == 0) red[4 + (tid >> 6)] = sv;
  __syncthreads();
  const float S = red[4] + red[5] + red[6] + red[7];
  const float inv = 1.0f / S;
  ap2[(size_t)((i0 >> 4) * 288 + o) * 16 + (i0 & 15)] = __float2bfloat16(e0 * inv);
  if (i1 < KP)
    ap2[(size_t)((i1 >> 4) * 288 + o) * 16 + (i1 & 15)] =
        __float2bfloat16(has1 ? e1 * inv : 0.f);
}

// ---------------- kernel T: X -> Xt[b][ks][t][k16] via LDS tile ----------------
// Block: 64 t x 288 i. Reads coalesced (wave = 64 consecutive t); writes are
// 2KB-contiguous runs per (ks, 64t). LDS row stride 592 B (16B-aligned).
__global__ __launch_bounds__(256) void k_trans(const float* __restrict__ X,
                                               char* __restrict__ Xt) {
  __shared__ __align__(16) char lds[64 * 592];
  const int tid = threadIdx.x;
  const int t0 = blockIdx.x * 64;
  const int b = blockIdx.y;
  const float* Xb = X + (size_t)b * C_IN * T_DIM;
  const int tt = tid & 63, ig = tid >> 6;
  #pragma unroll 4
  for (int p = 0; p < 36; ++p) {
    const int i = p * 8 + ig * 2;
    const float v0 = (i < C_IN) ? Xb[(size_t)i * T_DIM + t0 + tt] : 0.f;
    const float v1 = (i + 1 < C_IN) ? Xb[(size_t)(i + 1) * T_DIM + t0 + tt] : 0.f;
    const unsigned pk = (unsigned)(unsigned short)f2bf(v0)
                      | ((unsigned)(unsigned short)f2bf(v1) << 16);
    *(unsigned*)(lds + tt * 592 + i * 2) = pk;
  }
  __syncthreads();
  char* XtB = Xt + (size_t)b * XT_PER_B;
  #pragma unroll
  for (int j = 0; j < 5; ++j) {
    const int item = j * 256 + tid;          // item = ks*64 + tt2
    if (item < NKS * 64) {
      const int tt2 = item & 63, ks = item >> 6;
      const char* src = lds + tt2 * 592 + ks * 32;
      char* dst = XtB + (size_t)ks * XT_KS_STRIDE + (size_t)(t0 + tt2) * 32;
      *(float4*)(dst)      = *(const float4*)(src);
      *(float4*)(dst + 16) = *(const float4*)(src + 16);
    }
  }
}

// ---------------- kernel 2: out[b] = a @ X[b] -- every load wave-coalesced ----------------
// Grid (ob:3, tb:16, b:128), ob fastest (B-sharers co-resident). Block = 4 waves;
// wave w owns t-block tb*4+w (32 t). Per ks: 1 B-frag + 3 A-frag loads, each a
// contiguous 1KB wave footprint (lane = 16B). Depth-2 register pipeline.
__global__ __launch_bounds__(256) void k_gemm3(const __hip_bfloat16* __restrict__ ap2,
    const char* __restrict__ Xt, float* __restrict__ out) {
  const int tid = threadIdx.x;
  const int lane = tid & 63, w = tid >> 6;
  const int l32 = lane & 31, lh = lane >> 5;
  const int ob = blockIdx.x;   // 0..2
  const int tb = blockIdx.y;   // 0..15
  const int b  = blockIdx.z;   // 0..127

  const int tblk = tb * 4 + w;
  const char* Bbase = Xt + (size_t)b * XT_PER_B + tblk * 1024 + l32 * 32 + lh * 16;
  const char* Abase = (const char*)ap2 + (ob * 96 + l32) * 32 + lh * 16;

  f32x16 acc[3] = {};
  bf16x8 Bf[3], Af[3][3];

  // prologue: ks = 0, 1
  Bf[0]    = *(const bf16x8*)(Bbase);
  Af[0][0] = *(const bf16x8*)(Abase);
  Af[0][1] = *(const bf16x8*)(Abase + 1024);
  Af[0][2] = *(const bf16x8*)(Abase + 2048);
  Bf[1]    = *(const bf16x8*)(Bbase + XT_KS_STRIDE);
  Af[1][0] = *(const bf16x8*)(Abase + APR2_KS_STRIDE);
  Af[1][1] = *(const bf16x8*)(Abase + APR2_KS_STRIDE + 1024);
  Af[1][2] = *(const bf16x8*)(Abase + APR2_KS_STRIDE + 2048);
  __builtin_amdgcn_sched_barrier(0);

  #pragma unroll
  for (int ks = 0; ks < NKS; ++ks) {
    const int cur = ks % 3;
    if (ks + 2 < NKS) {
      const int nxt = (ks + 2) % 3;
      Bf[nxt]    = *(const bf16x8*)(Bbase + (size_t)(ks + 2) * XT_KS_STRIDE);
      Af[nxt][0] = *(const bf16x8*)(Abase + (ks + 2) * APR2_KS_STRIDE);
      Af[nxt][1] = *(const bf16x8*)(Abase + (ks + 2) * APR2_KS_STRIDE + 1024);
      Af[nxt][2] = *(const bf16x8*)(Abase + (ks + 2) * APR2_KS_STRIDE + 2048);
    }
    __builtin_amdgcn_sched_barrier(0);
    acc[0] = __builtin_amdgcn_mfma_f32_32x32x16_bf16(Af[cur][0], Bf[cur], acc[0], 0, 0, 0);
    acc[1] = __builtin_amdgcn_mfma_f32_32x32x16_bf16(Af[cur][1], Bf[cur], acc[1], 0, 0, 0);
    acc[2] = __builtin_amdgcn_mfma_f32_32x32x16_bf16(Af[cur][2], Bf[cur], acc[2], 0, 0, 0);
    __builtin_amdgcn_sched_barrier(0);
  }

  // epilogue: C/D layout (32x32): col = l&31 -> t, row = (r&3) + 8*(r>>2) + 4*lh
  const int t = tblk * 32 + l32;
  float* outb = out + (size_t)b * C_OUT * T_DIM;
  #pragma unroll
  for (int mi = 0; mi < 3; ++mi)
    #pragma unroll
    for (int r = 0; r < 16; ++r) {
      const int o = ob * 96 + mi * 32 + (r & 3) + 8 * (r >> 2) + 4 * lh;
      if (o < C_OUT)
        outb[(size_t)o * T_DIM + t] = acc[mi][r];
    }
}

extern "C" void kernel_launch(void* const* d_in, const int* in_sizes, int n_in,
                              void* d_out, int out_size, void* d_ws, size_t ws_size,
                              hipStream_t stream) {
  const float* X  = (const float*)d_in[0];
  const float* zr = (const float*)d_in[1];
  const float* zi = (const float*)d_in[2];
  const float* x  = (const float*)d_in[3];
  const float* y  = (const float*)d_in[4];
  const float* xd = (const float*)d_in[5];
  const float* yd = (const float*)d_in[6];
  float* out = (float*)d_out;
  char* ws = (char*)d_ws;

  float* cosb = (float*)(ws + WS2_COS);
  float* sinb = (float*)(ws + WS2_SIN);
  float* part = (float*)(ws + WS2_PART);
  __hip_bfloat16* ap2 = (__hip_bfloat16*)(ws + WS2_APERM);
  char* Xt = ws;  // offset 0, 151 MB

  k_basis<<<dim3(273), dim3(256), 0, stream>>>(x, y, cosb, sinb);
  k_logits<<<dim3(5, 5, 8), dim3(256), 0, stream>>>(zr, zi, cosb, sinb, part);
  k_softmax<<<dim3(KP), dim3(256), 0, stream>>>(part, x, y, xd, yd, ap2);
  k_trans<<<dim3(32, 128), dim3(256), 0, stream>>>(X, Xt);
  k_gemm3<<<dim3(3, 16, 128), dim3(256), 0, stream>>>(ap2, Xt, out);
}

// Round 8
// 348.635 us; speedup vs baseline: 1.4590x; 1.1334x over previous
//
#include <hip/hip_runtime.h>
#include <hip/hip_bf16.h>
#include <math.h>

typedef short s16x4 __attribute__((ext_vector_type(4)));
typedef short bf16x8 __attribute__((ext_vector_type(8)));
typedef float f32x16 __attribute__((ext_vector_type(16)));

#define C_IN 273
#define C_OUT 270
#define T_DIM 2048
#define KP 288            // padded C_in (18 k-slices of 16)
#define NKS 18

// ---------- workspace layout ----------
// Xt: bf16 [b][ks:18][t:2048][k:16]  (coalesced GEMM B-fragments)
#define XT_KS_STRIDE 65536u             // 2048*16*2 bytes
#define XT_PER_B 1179648u               // 18*65536
#define WS2_COS   150994944u
#define WS2_SIN   152113152u
#define WS2_PART  153231360u
#define WS2_APERM 155738112u            // bf16 [ks:18][o:288][k:16] = 165888 B
#define APR2_KS_STRIDE 9216u            // 288*16*2 bytes

// k_trans LDS: [k:16][t:2048] bf16, row stride 4104 B (1026 words == 2 mod 32)
#define TR_ROW 4104
#define TR_LDS (16 * TR_ROW)            // 65664 B -> 2 blocks/CU

__device__ __forceinline__ short f2bf(float f) {
  __hip_bfloat16 h = __float2bfloat16(f);
  short r; __builtin_memcpy(&r, &h, 2); return r;
}

// ---------------- kernel 1a: Fourier basis ----------------
__global__ void k_basis(const float* __restrict__ x, const float* __restrict__ y,
                        float* __restrict__ cosb, float* __restrict__ sinb) {
  const int i = blockIdx.x;
  const float xi = x[i], yi = y[i];
  const int base = threadIdx.x * 4;
  #pragma unroll
  for (int j = 0; j < 4; ++j) {
    const int kl = base + j;
    const float kf = (float)((kl & 31) + 1);
    const float lf = (float)((kl >> 5) + 1);
    const float ph = 6.28318530717958647692f * (kf * xi + lf * yi);
    float sn, cs;
    sincosf(ph, &sn, &cs);
    cosb[(size_t)i * 1024 + kl] = cs;
    sinb[(size_t)i * 1024 + kl] = sn;
  }
}

// ---------------- kernel 1b: logits partials ----------------
__global__ __launch_bounds__(256) void k_logits(const float* __restrict__ zr,
    const float* __restrict__ zi, const float* __restrict__ cosb,
    const float* __restrict__ sinb, float* __restrict__ part) {
  const int tx = threadIdx.x & 15, ty = threadIdx.x >> 4;
  const int ibase = blockIdx.x * 64 + tx * 4;
  const int obase = blockIdx.y * 64 + ty * 4;
  const int kl0 = (int)blockIdx.z * 128;
  int oc[4], ic[4];
  #pragma unroll
  for (int a = 0; a < 4; ++a) {
    oc[a] = min(obase + a, C_OUT - 1);
    ic[a] = min(ibase + a, C_IN - 1);
  }
  float acc[4][4] = {};
  for (int kl = kl0; kl < kl0 + 128; kl += 4) {
    float4 zr4[4], zi4[4], cb4[4], sb4[4];
    #pragma unroll
    for (int a = 0; a < 4; ++a) {
      zr4[a] = *(const float4*)(zr + (size_t)oc[a] * 1024 + kl);
      zi4[a] = *(const float4*)(zi + (size_t)oc[a] * 1024 + kl);
    }
    #pragma unroll
    for (int b = 0; b < 4; ++b) {
      cb4[b] = *(const float4*)(cosb + (size_t)ic[b] * 1024 + kl);
      sb4[b] = *(const float4*)(sinb + (size_t)ic[b] * 1024 + kl);
    }
    #pragma unroll
    for (int a = 0; a < 4; ++a)
      #pragma unroll
      for (int b = 0; b < 4; ++b)
        acc[a][b] += zr4[a].x * cb4[b].x + zr4[a].y * cb4[b].y
                   + zr4[a].z * cb4[b].z + zr4[a].w * cb4[b].w
                   + zi4[a].x * sb4[b].x + zi4[a].y * sb4[b].y
                   + zi4[a].z * sb4[b].z + zi4[a].w * sb4[b].w;
  }
  #pragma unroll
  for (int a = 0; a < 4; ++a)
    #pragma unroll
    for (int b = 0; b < 4; ++b) {
      const int o = obase + a, i = ibase + b;
      if (o < C_OUT && i < C_IN)
        part[((size_t)blockIdx.z * 272 + o) * 288 + i] = acc[a][b];
    }
}

// ---------------- kernel 1c: mask + softmax -> aperm2[ks][o][k] bf16 ----------------
__global__ __launch_bounds__(256) void k_softmax(const float* __restrict__ part,
    const float* __restrict__ x, const float* __restrict__ y,
    const float* __restrict__ xdp, const float* __restrict__ ydp,
    __hip_bfloat16* __restrict__ ap2) {
  const int o = blockIdx.x;            // 0..287
  const int tid = threadIdx.x;
  if (o >= C_OUT) {
    for (int s = tid; s < KP; s += 256)
      ap2[(size_t)((s >> 4) * 288 + o) * 16 + (s & 15)] = __float2bfloat16(0.f);
    return;
  }
  __shared__ float red[8];
  const float xd = xdp[0], yd = ydp[0];
  const int i0 = tid, i1 = tid + 256;
  float v0, v1 = 0.f;
  {
    float s = 0.f;
    #pragma unroll
    for (int c = 0; c < 8; ++c) s += part[((size_t)c * 272 + o) * 288 + i0];
    const float dx = xd - x[i0], dy = yd - y[i0];
    v0 = (dx * dx + dy * dy < 0.1f) ? 0.f : s;
  }
  const bool has1 = (i1 < C_IN);
  if (has1) {
    float s = 0.f;
    #pragma unroll
    for (int c = 0; c < 8; ++c) s += part[((size_t)c * 272 + o) * 288 + i1];
    const float dx = xd - x[i1], dy = yd - y[i1];
    v1 = (dx * dx + dy * dy < 0.1f) ? 0.f : s;
  }
  float mv = has1 ? fmaxf(v0, v1) : v0;
  #pragma unroll
  for (int off = 32; off >= 1; off >>= 1) mv = fmaxf(mv, __shfl_down(mv, off));
  if ((tid & 63) == 0) red[tid >> 6] = mv;
  __syncthreads();
  const float M = fmaxf(fmaxf(red[0], red[1]), fmaxf(red[2], red[3]));
  const float e0 = expf(v0 - M);
  const float e1 = has1 ? expf(v1 - M) : 0.f;
  float sv = e0 + e1;
  #pragma unroll
  for (int off = 32; off >= 1; off >>= 1) sv += __shfl_down(sv, off);
  __syncthreads();
  if ((tid & 63) == 0) red[4 + (tid >> 6)] = sv;
  __syncthreads();
  const float S = red[4] + red[5] + red[6] + red[7];
  const float inv = 1.0f / S;
  ap2[(size_t)((i0 >> 4) * 288 + o) * 16 + (i0 & 15)] = __float2bfloat16(e0 * inv);
  if (i1 < KP)
    ap2[(size_t)((i1 >> 4) * 288 + o) * 16 + (i1 & 15)] =
        __float2bfloat16(has1 ? e1 * inv : 0.f);
}

// ---------------- kernel T: X -> Xt[b][ks][t][k16], contiguity-first ----------------
// Block = one (b, ks): 16 i-rows x 2048 t. Reads: 16 x 8KB sequential (float4/lane).
// LDS [k:16][t:2048] bf16, stride 4104 B: writes 4-way worst, reads conflict-free.
// Writes: 64KB contiguous per block, 1KB consecutive per wave instruction.
__global__ __launch_bounds__(256) void k_trans(const float* __restrict__ X,
                                               char* __restrict__ Xt) {
  __shared__ __align__(16) char lds[TR_LDS];
  const int tid = threadIdx.x;
  const int ks = blockIdx.x;           // 0..17
  const int b  = blockIdx.y;           // 0..127
  const float* Xb = X + (size_t)b * C_IN * T_DIM;

  const int ri = tid >> 4;             // 0..15 (local i / k)
  const int tq = tid & 15;             // 16 float4-columns
  const int gi = ks * 16 + ri;
  const bool valid = (gi < C_IN);
  const float* src = Xb + (size_t)gi * T_DIM + tq * 4;
  char* ldsrow = lds + ri * TR_ROW + tq * 8;

  #pragma unroll 8
  for (int p = 0; p < 32; ++p) {
    float4 v = valid ? *(const float4*)(src + p * 64) : make_float4(0.f, 0.f, 0.f, 0.f);
    s16x4 pk;
    pk[0] = f2bf(v.x); pk[1] = f2bf(v.y); pk[2] = f2bf(v.z); pk[3] = f2bf(v.w);
    *(s16x4*)(ldsrow + p * 128) = pk;
  }
  __syncthreads();

  // phase 2: u = it*256 + tid -> t = u>>1, half = u&1 (k-range half*8..half*8+7).
  // 8 u16 gathers (broadcast-paired, conflict-free) -> 1 fully-coalesced float4.
  char* dstB = Xt + (size_t)b * XT_PER_B + (size_t)ks * XT_KS_STRIDE;
  #pragma unroll
  for (int it = 0; it < 16; ++it) {
    const int u = it * 256 + tid;
    const int t = u >> 1, half = (u & 1) * 8;
    unsigned short w[8];
    #pragma unroll
    for (int r = 0; r < 8; ++r)
      w[r] = *(const unsigned short*)(lds + (half + r) * TR_ROW + t * 2);
    uint4 pk;
    pk.x = (unsigned)w[0] | ((unsigned)w[1] << 16);
    pk.y = (unsigned)w[2] | ((unsigned)w[3] << 16);
    pk.z = (unsigned)w[4] | ((unsigned)w[5] << 16);
    pk.w = (unsigned)w[6] | ((unsigned)w[7] << 16);
    *(uint4*)(dstB + (size_t)u * 16) = pk;
  }
}

// ---------------- kernel 2: out[b] = a @ X[b] -- every load wave-coalesced ----------------
// Flat grid 6144; L = (bid&7)*768 + (bid>>3) keeps the 3 ob-sharers of each
// (tb,b) on ONE XCD, adjacent in time (768%3==0) -> Xt re-reads hit L2.
__global__ __launch_bounds__(256) void k_gemm3(const __hip_bfloat16* __restrict__ ap2,
    const char* __restrict__ Xt, float* __restrict__ out) {
  const int tid = threadIdx.x;
  const int lane = tid & 63, w = tid >> 6;
  const int l32 = lane & 31, lh = lane >> 5;
  const int bid = blockIdx.x;
  const int L = (bid & 7) * 768 + (bid >> 3);
  const int ob = L % 3;
  const int rest = L / 3;              // 0..2047
  const int tb = rest & 15;
  const int b  = rest >> 4;            // 0..127

  const int tblk = tb * 4 + w;
  const char* Bbase = Xt + (size_t)b * XT_PER_B + tblk * 1024 + l32 * 32 + lh * 16;
  const char* Abase = (const char*)ap2 + (ob * 96 + l32) * 32 + lh * 16;

  f32x16 acc[3] = {};
  bf16x8 Bf[3], Af[3][3];

  // prologue: ks = 0, 1
  Bf[0]    = *(const bf16x8*)(Bbase);
  Af[0][0] = *(const bf16x8*)(Abase);
  Af[0][1] = *(const bf16x8*)(Abase + 1024);
  Af[0][2] = *(const bf16x8*)(Abase + 2048);
  Bf[1]    = *(const bf16x8*)(Bbase + XT_KS_STRIDE);
  Af[1][0] = *(const bf16x8*)(Abase + APR2_KS_STRIDE);
  Af[1][1] = *(const bf16x8*)(Abase + APR2_KS_STRIDE + 1024);
  Af[1][2] = *(const bf16x8*)(Abase + APR2_KS_STRIDE + 2048);
  __builtin_amdgcn_sched_barrier(0);

  #pragma unroll
  for (int ks = 0; ks < NKS; ++ks) {
    const int cur = ks % 3;
    if (ks + 2 < NKS) {
      const int nxt = (ks + 2) % 3;
      Bf[nxt]    = *(const bf16x8*)(Bbase + (size_t)(ks + 2) * XT_KS_STRIDE);
      Af[nxt][0] = *(const bf16x8*)(Abase + (ks + 2) * APR2_KS_STRIDE);
      Af[nxt][1] = *(const bf16x8*)(Abase + (ks + 2) * APR2_KS_STRIDE + 1024);
      Af[nxt][2] = *(const bf16x8*)(Abase + (ks + 2) * APR2_KS_STRIDE + 2048);
    }
    __builtin_amdgcn_sched_barrier(0);
    acc[0] = __builtin_amdgcn_mfma_f32_32x32x16_bf16(Af[cur][0], Bf[cur], acc[0], 0, 0, 0);
    acc[1] = __builtin_amdgcn_mfma_f32_32x32x16_bf16(Af[cur][1], Bf[cur], acc[1], 0, 0, 0);
    acc[2] = __builtin_amdgcn_mfma_f32_32x32x16_bf16(Af[cur][2], Bf[cur], acc[2], 0, 0, 0);
    __builtin_amdgcn_sched_barrier(0);
  }

  // epilogue: C/D layout (32x32): col = l&31 -> t, row = (r&3) + 8*(r>>2) + 4*lh
  const int t = tblk * 32 + l32;
  float* outb = out + (size_t)b * C_OUT * T_DIM;
  #pragma unroll
  for (int mi = 0; mi < 3; ++mi)
    #pragma unroll
    for (int r = 0; r < 16; ++r) {
      const int o = ob * 96 + mi * 32 + (r & 3) + 8 * (r >> 2) + 4 * lh;
      if (o < C_OUT)
        outb[(size_t)o * T_DIM + t] = acc[mi][r];
    }
}

extern "C" void kernel_launch(void* const* d_in, const int* in_sizes, int n_in,
                              void* d_out, int out_size, void* d_ws, size_t ws_size,
                              hipStream_t stream) {
  const float* X  = (const float*)d_in[0];
  const float* zr = (const float*)d_in[1];
  const float* zi = (const float*)d_in[2];
  const float* x  = (const float*)d_in[3];
  const float* y  = (const float*)d_in[4];
  const float* xd = (const float*)d_in[5];
  const float* yd = (const float*)d_in[6];
  float* out = (float*)d_out;
  char* ws = (char*)d_ws;

  float* cosb = (float*)(ws + WS2_COS);
  float* sinb = (float*)(ws + WS2_SIN);
  float* part = (float*)(ws + WS2_PART);
  __hip_bfloat16* ap2 = (__hip_bfloat16*)(ws + WS2_APERM);
  char* Xt = ws;  // offset 0, 151 MB

  k_basis<<<dim3(273), dim3(256), 0, stream>>>(x, y, cosb, sinb);
  k_logits<<<dim3(5, 5, 8), dim3(256), 0, stream>>>(zr, zi, cosb, sinb, part);
  k_softmax<<<dim3(KP), dim3(256), 0, stream>>>(part, x, y, xd, yd, ap2);
  k_trans<<<dim3(18, 128), dim3(256), 0, stream>>>(X, Xt);
  k_gemm3<<<dim3(6144), dim3(256), 0, stream>>>(ap2, Xt, out);
}

// Round 9
// 324.553 us; speedup vs baseline: 1.5672x; 1.0742x over previous
//
#include <hip/hip_runtime.h>
#include <hip/hip_bf16.h>
#include <math.h>

typedef short s16x4 __attribute__((ext_vector_type(4)));
typedef short bf16x8 __attribute__((ext_vector_type(8)));
typedef float f32x16 __attribute__((ext_vector_type(16)));

#define C_IN 273
#define C_OUT 270
#define T_DIM 2048
#define KP 288            // padded C_in (18 k-slices of 16)
#define NKS 18

// ---------- workspace layout ----------
// Xt: bf16 [b][g:64][ks:18][tg:32][k:16]  (g = t>>5; per-wave B-stream sequential)
#define XT_G_STRIDE 18432u              // 18*1024 bytes
#define XT_PER_B 1179648u               // 64*18432
#define WS2_COS   150994944u
#define WS2_SIN   152113152u
#define WS2_PART  153231360u
#define WS2_APERM 155738112u            // bf16 [ks:18][o:288][k:16] = 165888 B
#define APR2_KS_STRIDE 9216u            // 288*16*2 bytes

// k_trans LDS: [k:16][t:2048] bf16, row stride 4104 B
#define TR_ROW 4104
#define TR_LDS (16 * TR_ROW)            // 65664 B -> 2 blocks/CU

__device__ __forceinline__ short f2bf(float f) {
  __hip_bfloat16 h = __float2bfloat16(f);
  short r; __builtin_memcpy(&r, &h, 2); return r;
}

// ---------------- kernel 1a: Fourier basis ----------------
__global__ void k_basis(const float* __restrict__ x, const float* __restrict__ y,
                        float* __restrict__ cosb, float* __restrict__ sinb) {
  const int i = blockIdx.x;
  const float xi = x[i], yi = y[i];
  const int base = threadIdx.x * 4;
  #pragma unroll
  for (int j = 0; j < 4; ++j) {
    const int kl = base + j;
    const float kf = (float)((kl & 31) + 1);
    const float lf = (float)((kl >> 5) + 1);
    const float ph = 6.28318530717958647692f * (kf * xi + lf * yi);
    float sn, cs;
    sincosf(ph, &sn, &cs);
    cosb[(size_t)i * 1024 + kl] = cs;
    sinb[(size_t)i * 1024 + kl] = sn;
  }
}

// ---------------- kernel 1b: logits partials (32x32 tiles, 648 blocks) ----------------
__global__ __launch_bounds__(256) void k_logits(const float* __restrict__ zr,
    const float* __restrict__ zi, const float* __restrict__ cosb,
    const float* __restrict__ sinb, float* __restrict__ part) {
  const int tx = threadIdx.x & 15, ty = threadIdx.x >> 4;
  const int ibase = blockIdx.x * 32 + tx * 2;
  const int obase = blockIdx.y * 32 + ty * 2;
  const int kl0 = (int)blockIdx.z * 128;
  int oc[2], ic[2];
  #pragma unroll
  for (int a = 0; a < 2; ++a) {
    oc[a] = min(obase + a, C_OUT - 1);
    ic[a] = min(ibase + a, C_IN - 1);
  }
  float acc[2][2] = {};
  for (int kl = kl0; kl < kl0 + 128; kl += 4) {
    float4 zr4[2], zi4[2], cb4[2], sb4[2];
    #pragma unroll
    for (int a = 0; a < 2; ++a) {
      zr4[a] = *(const float4*)(zr + (size_t)oc[a] * 1024 + kl);
      zi4[a] = *(const float4*)(zi + (size_t)oc[a] * 1024 + kl);
    }
    #pragma unroll
    for (int b = 0; b < 2; ++b) {
      cb4[b] = *(const float4*)(cosb + (size_t)ic[b] * 1024 + kl);
      sb4[b] = *(const float4*)(sinb + (size_t)ic[b] * 1024 + kl);
    }
    #pragma unroll
    for (int a = 0; a < 2; ++a)
      #pragma unroll
      for (int b = 0; b < 2; ++b)
        acc[a][b] += zr4[a].x * cb4[b].x + zr4[a].y * cb4[b].y
                   + zr4[a].z * cb4[b].z + zr4[a].w * cb4[b].w
                   + zi4[a].x * sb4[b].x + zi4[a].y * sb4[b].y
                   + zi4[a].z * sb4[b].z + zi4[a].w * sb4[b].w;
  }
  #pragma unroll
  for (int a = 0; a < 2; ++a)
    #pragma unroll
    for (int b = 0; b < 2; ++b) {
      const int o = obase + a, i = ibase + b;
      if (o < C_OUT && i < C_IN)
        part[((size_t)blockIdx.z * 272 + o) * 288 + i] = acc[a][b];
    }
}

// ---------------- kernel 1c: mask + softmax -> aperm2[ks][o][k] bf16 ----------------
__global__ __launch_bounds__(256) void k_softmax(const float* __restrict__ part,
    const float* __restrict__ x, const float* __restrict__ y,
    const float* __restrict__ xdp, const float* __restrict__ ydp,
    __hip_bfloat16* __restrict__ ap2) {
  const int o = blockIdx.x;            // 0..287
  const int tid = threadIdx.x;
  if (o >= C_OUT) {
    for (int s = tid; s < KP; s += 256)
      ap2[(size_t)((s >> 4) * 288 + o) * 16 + (s & 15)] = __float2bfloat16(0.f);
    return;
  }
  __shared__ float red[8];
  const float xd = xdp[0], yd = ydp[0];
  const int i0 = tid, i1 = tid + 256;
  float v0, v1 = 0.f;
  {
    float s = 0.f;
    #pragma unroll
    for (int c = 0; c < 8; ++c) s += part[((size_t)c * 272 + o) * 288 + i0];
    const float dx = xd - x[i0], dy = yd - y[i0];
    v0 = (dx * dx + dy * dy < 0.1f) ? 0.f : s;
  }
  const bool has1 = (i1 < C_IN);
  if (has1) {
    float s = 0.f;
    #pragma unroll
    for (int c = 0; c < 8; ++c) s += part[((size_t)c * 272 + o) * 288 + i1];
    const float dx = xd - x[i1], dy = yd - y[i1];
    v1 = (dx * dx + dy * dy < 0.1f) ? 0.f : s;
  }
  float mv = has1 ? fmaxf(v0, v1) : v0;
  #pragma unroll
  for (int off = 32; off >= 1; off >>= 1) mv = fmaxf(mv, __shfl_down(mv, off));
  if ((tid & 63) == 0) red[tid >> 6] = mv;
  __syncthreads();
  const float M = fmaxf(fmaxf(red[0], red[1]), fmaxf(red[2], red[3]));
  const float e0 = expf(v0 - M);
  const float e1 = has1 ? expf(v1 - M) : 0.f;
  float sv = e0 + e1;
  #pragma unroll
  for (int off = 32; off >= 1; off >>= 1) sv += __shfl_down(sv, off);
  __syncthreads();
  if ((tid & 63) == 0) red[4 + (tid >> 6)] = sv;
  __syncthreads();
  const float S = red[4] + red[5] + red[6] + red[7];
  const float inv = 1.0f / S;
  ap2[(size_t)((i0 >> 4) * 288 + o) * 16 + (i0 & 15)] = __float2bfloat16(e0 * inv);
  if (i1 < KP)
    ap2[(size_t)((i1 >> 4) * 288 + o) * 16 + (i1 & 15)] =
        __float2bfloat16(has1 ? e1 * inv : 0.f);
}

// ---------------- kernel T: X -> Xt[b][g][ks][tg][k16] ----------------
// Block = one (b, ks): reads 16 x 8KB sequential; writes 64KB contiguous-ish
// (1KB per wave instruction, runs ordered by g).
__global__ __launch_bounds__(256) void k_trans(const float* __restrict__ X,
                                               char* __restrict__ Xt) {
  __shared__ __align__(16) char lds[TR_LDS];
  const int tid = threadIdx.x;
  const int ks = blockIdx.x;           // 0..17
  const int b  = blockIdx.y;           // 0..127
  const float* Xb = X + (size_t)b * C_IN * T_DIM;

  const int ri = tid >> 4;             // 0..15 (local k)
  const int tq = tid & 15;
  const int gi = ks * 16 + ri;
  const bool valid = (gi < C_IN);
  const float* src = Xb + (size_t)gi * T_DIM + tq * 4;
  char* ldsrow = lds + ri * TR_ROW + tq * 8;

  #pragma unroll 8
  for (int p = 0; p < 32; ++p) {
    float4 v = valid ? *(const float4*)(src + p * 64) : make_float4(0.f, 0.f, 0.f, 0.f);
    s16x4 pk;
    pk[0] = f2bf(v.x); pk[1] = f2bf(v.y); pk[2] = f2bf(v.z); pk[3] = f2bf(v.w);
    *(s16x4*)(ldsrow + p * 128) = pk;
  }
  __syncthreads();

  // phase 2: u = it*256+tid -> t = u>>1, half = u&1; g = t>>5, tg = t&31
  char* dstB = Xt + (size_t)b * XT_PER_B + (size_t)ks * 1024u;
  #pragma unroll
  for (int it = 0; it < 16; ++it) {
    const int u = it * 256 + tid;
    const int t = u >> 1, half = (u & 1) * 8;
    const int g = t >> 5, tg = t & 31;
    unsigned short w[8];
    #pragma unroll
    for (int r = 0; r < 8; ++r)
      w[r] = *(const unsigned short*)(lds + (half + r) * TR_ROW + t * 2);
    uint4 pk;
    pk.x = (unsigned)w[0] | ((unsigned)w[1] << 16);
    pk.y = (unsigned)w[2] | ((unsigned)w[3] << 16);
    pk.z = (unsigned)w[4] | ((unsigned)w[5] << 16);
    pk.w = (unsigned)w[6] | ((unsigned)w[7] << 16);
    *(uint4*)(dstB + (size_t)g * XT_G_STRIDE + tg * 32 + half * 2) = pk;
  }
}

// ---------------- kernel 2: out[b] = a @ X[b] -- wide waves, streaming B ----------------
// Wave tile: 96 o x 64 t (6 MFMA/ks). B-fragments stream sequentially:
// base + ks*1024 within the wave's two 18KB g-regions. Depth-2 B, depth-1 A.
__global__ __launch_bounds__(256) void k_gemm4(const __hip_bfloat16* __restrict__ ap2,
    const char* __restrict__ Xt, float* __restrict__ out) {
  const int tid = threadIdx.x;
  const int lane = tid & 63, w = tid >> 6;
  const int l32 = lane & 31, lh = lane >> 5;
  const int bid = blockIdx.x;          // 0..3071
  const int L = (bid & 7) * 384 + (bid >> 3);   // XCD-cohort; 384%3==0
  const int ob = L % 3;
  const int rest = L / 3;              // 0..1023
  const int tb = rest & 7;
  const int b  = rest >> 3;            // 0..127

  const int g0 = tb * 8 + w * 2;       // wave's two t-groups: g0, g0+1
  const char* Bb0 = Xt + (size_t)b * XT_PER_B + (size_t)g0 * XT_G_STRIDE + l32 * 32 + lh * 16;
  const char* Bb1 = Bb0 + XT_G_STRIDE;
  const char* Ab  = (const char*)ap2 + (ob * 96 + l32) * 32 + lh * 16;

  f32x16 acc[3][2] = {};
  bf16x8 Bf[3][2], Af[2][3];

  // prologue: B for ks=0,1; A for ks=0
  Bf[0][0] = *(const bf16x8*)(Bb0);
  Bf[0][1] = *(const bf16x8*)(Bb1);
  Bf[1][0] = *(const bf16x8*)(Bb0 + 1024);
  Bf[1][1] = *(const bf16x8*)(Bb1 + 1024);
  Af[0][0] = *(const bf16x8*)(Ab);
  Af[0][1] = *(const bf16x8*)(Ab + 1024);
  Af[0][2] = *(const bf16x8*)(Ab + 2048);
  __builtin_amdgcn_sched_barrier(0);

  #pragma unroll
  for (int ks = 0; ks < NKS; ++ks) {
    const int c3 = ks % 3, c2 = ks % 2;
    if (ks + 2 < NKS) {
      const int n3 = (ks + 2) % 3;
      Bf[n3][0] = *(const bf16x8*)(Bb0 + (ks + 2) * 1024);
      Bf[n3][1] = *(const bf16x8*)(Bb1 + (ks + 2) * 1024);
    }
    if (ks + 1 < NKS) {
      const int n2 = (ks + 1) % 2;
      Af[n2][0] = *(const bf16x8*)(Ab + (ks + 1) * APR2_KS_STRIDE);
      Af[n2][1] = *(const bf16x8*)(Ab + (ks + 1) * APR2_KS_STRIDE + 1024);
      Af[n2][2] = *(const bf16x8*)(Ab + (ks + 1) * APR2_KS_STRIDE + 2048);
    }
    __builtin_amdgcn_sched_barrier(0);
    acc[0][0] = __builtin_amdgcn_mfma_f32_32x32x16_bf16(Af[c2][0], Bf[c3][0], acc[0][0], 0, 0, 0);
    acc[0][1] = __builtin_amdgcn_mfma_f32_32x32x16_bf16(Af[c2][0], Bf[c3][1], acc[0][1], 0, 0, 0);
    acc[1][0] = __builtin_amdgcn_mfma_f32_32x32x16_bf16(Af[c2][1], Bf[c3][0], acc[1][0], 0, 0, 0);
    acc[1][1] = __builtin_amdgcn_mfma_f32_32x32x16_bf16(Af[c2][1], Bf[c3][1], acc[1][1], 0, 0, 0);
    acc[2][0] = __builtin_amdgcn_mfma_f32_32x32x16_bf16(Af[c2][2], Bf[c3][0], acc[2][0], 0, 0, 0);
    acc[2][1] = __builtin_amdgcn_mfma_f32_32x32x16_bf16(Af[c2][2], Bf[c3][1], acc[2][1], 0, 0, 0);
    __builtin_amdgcn_sched_barrier(0);
  }

  // epilogue: C/D (32x32): col = l32 -> t, row = (r&3) + 8*(r>>2) + 4*lh
  float* outb = out + (size_t)b * C_OUT * T_DIM;
  #pragma unroll
  for (int mi = 0; mi < 3; ++mi)
    #pragma unroll
    for (int n = 0; n < 2; ++n) {
      const int t = (g0 + n) * 32 + l32;
      #pragma unroll
      for (int r = 0; r < 16; ++r) {
        const int o = ob * 96 + mi * 32 + (r & 3) + 8 * (r >> 2) + 4 * lh;
        if (o < C_OUT)
          outb[(size_t)o * T_DIM + t] = acc[mi][n][r];
      }
    }
}

extern "C" void kernel_launch(void* const* d_in, const int* in_sizes, int n_in,
                              void* d_out, int out_size, void* d_ws, size_t ws_size,
                              hipStream_t stream) {
  const float* X  = (const float*)d_in[0];
  const float* zr = (const float*)d_in[1];
  const float* zi = (const float*)d_in[2];
  const float* x  = (const float*)d_in[3];
  const float* y  = (const float*)d_in[4];
  const float* xd = (const float*)d_in[5];
  const float* yd = (const float*)d_in[6];
  float* out = (float*)d_out;
  char* ws = (char*)d_ws;

  float* cosb = (float*)(ws + WS2_COS);
  float* sinb = (float*)(ws + WS2_SIN);
  float* part = (float*)(ws + WS2_PART);
  __hip_bfloat16* ap2 = (__hip_bfloat16*)(ws + WS2_APERM);
  char* Xt = ws;  // offset 0, 151 MB

  k_basis<<<dim3(273), dim3(256), 0, stream>>>(x, y, cosb, sinb);
  k_logits<<<dim3(9, 9, 8), dim3(256), 0, stream>>>(zr, zi, cosb, sinb, part);
  k_softmax<<<dim3(KP), dim3(256), 0, stream>>>(part, x, y, xd, yd, ap2);
  k_trans<<<dim3(18, 128), dim3(256), 0, stream>>>(X, Xt);
  k_gemm4<<<dim3(3072), dim3(256), 0, stream>>>(ap2, Xt, out);
}